// Round 4
// baseline (307.145 us; speedup 1.0000x reference)
//
#include <hip/hip_runtime.h>

typedef __attribute__((ext_vector_type(8))) short bf16x8;
typedef __attribute__((ext_vector_type(4))) float f32x4;

#define D_IN 256
#define D_OUT 256
#define KDIM 512
#define TM 16
#define LDS_STRIDE (KDIM + 8)

static __device__ __forceinline__ unsigned short f2bf(float f) {
    union { float f; unsigned int u; } x; x.f = f;
    unsigned int r = (x.u + 0x7FFFu + ((x.u >> 16) & 1u)) >> 16;
    return (unsigned short)r;
}

// ---------------- zero deg + pack W fragments (one dispatch, replaces slow fill node) ----------------
// wfrag layout: wf[((nt*16 + kk)*64 + lane)*8 + j] = bf16(W[kk*32 + (lane>>4)*8 + j][nt*16 + (lane&15)])
__global__ void zero_wfrag_kernel(int* __restrict__ deg, int n, int zblocks,
                                  const float* __restrict__ W, unsigned short* __restrict__ wf) {
    int b = blockIdx.x;
    if (b < zblocks) {
        int i = b * 256 + threadIdx.x;
        if (i < n) deg[i] = 0;
    } else {
        int t = (b - zblocks) * 256 + threadIdx.x;
        if (t < 16 * 16 * 64) {
            int l  = t & 63;
            int kk = (t >> 6) & 15;
            int nt = t >> 10;
            int c  = nt * 16 + (l & 15);
            int kb = kk * 32 + (l >> 4) * 8;
            union { unsigned short u[8]; uint4 v; } pk;
#pragma unroll
            for (int j = 0; j < 8; ++j) pk.u[j] = f2bf(W[(size_t)(kb + j) * D_OUT + c]);
            *reinterpret_cast<uint4*>(&wf[(size_t)t * 8]) = pk.v;
        }
    }
}

__global__ void count_kernel(const int* __restrict__ dst, int* __restrict__ deg, int E) {
    int e = blockIdx.x * 256 + threadIdx.x;
    if (e < E) atomicAdd(&deg[dst[e]], 1);
}

// exclusive scan; writes offsets[0..n] and cursor[i]=offsets[i]
__global__ void scan_kernel(const int* __restrict__ deg, int* __restrict__ offsets,
                            int* __restrict__ cursor, int n) {
    __shared__ int ssum[1024];
    int t = threadIdx.x;
    int C = (n + 1023) >> 10;
    int lo = t * C;
    int hi = lo + C; if (hi > n) hi = n;
    int s = 0;
    for (int i = lo; i < hi; ++i) s += deg[i];
    int v = s;
    ssum[t] = v;
    __syncthreads();
    for (int off = 1; off < 1024; off <<= 1) {
        int u = (t >= off) ? ssum[t - off] : 0;
        __syncthreads();
        v += u;
        ssum[t] = v;
        __syncthreads();
    }
    int run = v - s;   // exclusive prefix
    for (int i = lo; i < hi; ++i) { offsets[i] = run; cursor[i] = run; run += deg[i]; }
    if (t == 1023) offsets[n] = run;
}

// writes int2{edge_id, src_id}; cursor pre-seeded with offsets -> absolute position
__global__ void scatter_kernel(const int* __restrict__ dst, const int* __restrict__ src_idx,
                               int* __restrict__ cursor, int2* __restrict__ rec, int E) {
    int e = blockIdx.x * 256 + threadIdx.x;
    if (e < E) {
        int p = atomicAdd(&cursor[dst[e]], 1);
        rec[p] = make_int2(e, src_idx[e]);
    }
}

#define ACC8(P) do {                                                    \
    float4 _v0 = *(const float4*)(P);                                   \
    float4 _v1 = *(const float4*)((P) + 4);                             \
    a0.x += _v0.x; a0.y += _v0.y; a0.z += _v0.z; a0.w += _v0.w;         \
    a1.x += _v1.x; a1.y += _v1.y; a1.z += _v1.z; a1.w += _v1.w;         \
} while (0)

// Both shfls execute unconditionally across the full wave (convergent ops must
// not sit inside the lane-divergent ternary); select on the RESULTS.
#define EPTR(Q, P)                                                      \
    int _e_##Q = __shfl(id.x, (P));                                     \
    int _s_##Q = __shfl(id.y, (P));                                     \
    const float* Q = fbase + (size_t)(half ? _e_##Q : _s_##Q) * D_IN

// ---------------- fused aggregate + GEMM ----------------
__global__ __launch_bounds__(256) void fused_kernel(
    const float* __restrict__ src_feats,
    const float* __restrict__ edge_feats,
    const int2* __restrict__ rec,
    const int* __restrict__ offsets,
    const unsigned short* __restrict__ wfrag,
    const float* __restrict__ bias,
    float* __restrict__ out,
    int n_dst)
{
    __shared__ __align__(16) unsigned short aggs[TM * LDS_STRIDE];  // padded stride

    const int tid = threadIdx.x;
    const int wv = tid >> 6;
    const int ln = tid & 63;
    const int base = blockIdx.x * TM;

    // preload the block's 17 row offsets, lane-parallel
    int off_l = 0;
    {
        int i = base + ln;
        if (i > n_dst) i = n_dst;
        if (ln <= TM) off_l = offsets[i];
    }

    const int half = ln >> 5;            // 0: src half, 1: edge half
    const int sub  = (ln & 31) * 8;      // 8 floats per lane
    const float* fbase = (half ? edge_feats : src_feats) + sub;

    // prefetch first row's id records
    int sN = __shfl(off_l, wv);
    int eN = __shfl(off_l, wv + 1);
    int2 idN = make_int2(0, 0);
    { int c0 = eN - sN; if (c0 > 64) c0 = 64; if (ln < c0) idN = rec[sN + ln]; }

    // ---- aggregation: wave wv owns rows wv, wv+4, wv+8, wv+12 ----
    for (int r = wv; r < TM; r += 4) {
        int s = sN, eend = eN;
        int2 id = idN;
        if (r + 4 < TM) {                        // prefetch next row's ids now
            sN = __shfl(off_l, r + 4);
            eN = __shfl(off_l, r + 5);
            idN = make_int2(0, 0);
            int c0 = eN - sN; if (c0 > 64) c0 = 64;
            if (ln < c0) idN = rec[sN + ln];
        }
        float4 a0 = make_float4(0.f, 0.f, 0.f, 0.f);
        float4 a1 = make_float4(0.f, 0.f, 0.f, 0.f);

        for (int c = s; c < eend; c += 64) {
            int cnt = eend - c; if (cnt > 64) cnt = 64;
            int p = 0;
            for (; p + 8 <= cnt; p += 8) {
                EPTR(q0, p + 0); EPTR(q1, p + 1); EPTR(q2, p + 2); EPTR(q3, p + 3);
                EPTR(q4, p + 4); EPTR(q5, p + 5); EPTR(q6, p + 6); EPTR(q7, p + 7);
                ACC8(q0); ACC8(q1); ACC8(q2); ACC8(q3);
                ACC8(q4); ACC8(q5); ACC8(q6); ACC8(q7);
            }
            for (; p + 2 <= cnt; p += 2) {
                EPTR(q0, p); EPTR(q1, p + 1);
                ACC8(q0); ACC8(q1);
            }
            for (; p < cnt; ++p) {
                EPTR(q0, p);
                ACC8(q0);
            }
            if (c + 64 < eend) {                 // next chunk (rare: deg > 64)
                int cn = eend - c - 64; if (cn > 64) cn = 64;
                id = make_int2(0, 0);
                if (ln < cn) id = rec[c + 64 + ln];
            }
        }

        union { unsigned short u[8]; uint4 v; } pk;
        pk.u[0] = f2bf(a0.x); pk.u[1] = f2bf(a0.y); pk.u[2] = f2bf(a0.z); pk.u[3] = f2bf(a0.w);
        pk.u[4] = f2bf(a1.x); pk.u[5] = f2bf(a1.y); pk.u[6] = f2bf(a1.z); pk.u[7] = f2bf(a1.w);
        int col = half * 256 + sub;
        *reinterpret_cast<uint4*>(&aggs[r * LDS_STRIDE + col]) = pk.v;
    }
    __syncthreads();

    // ---- GEMM: out[16 x 256] = aggs[16 x 512] @ W[512 x 256] (bf16 MFMA) ----
    const int lrow = ln & 15;
    const int lgrp = ln >> 4;
    f32x4 acc[4];
#pragma unroll
    for (int n = 0; n < 4; ++n) acc[n] = (f32x4)(0.0f);

#pragma unroll
    for (int kk = 0; kk < 16; ++kk) {
        int kb = kk * 32 + lgrp * 8;
        bf16x8 A0 = *reinterpret_cast<const bf16x8*>(&aggs[lrow * LDS_STRIDE + kb]);
#pragma unroll
        for (int n = 0; n < 4; ++n) {
            int nt = wv * 4 + n;
            bf16x8 B = *reinterpret_cast<const bf16x8*>(&wfrag[(((size_t)nt * 16 + kk) * 64 + ln) * 8]);
            acc[n] = __builtin_amdgcn_mfma_f32_16x16x32_bf16(A0, B, acc[n], 0, 0, 0);
        }
    }

    // ---- epilogue: norm (recomputed from off_l) + bias, fp32 store ----
    float bias_r[4];
#pragma unroll
    for (int n = 0; n < 4; ++n) bias_r[n] = bias[wv * 64 + n * 16 + lrow];

#pragma unroll
    for (int j = 0; j < 4; ++j) {
        int r = lgrp * 4 + j;
        int dg = __shfl(off_l, r + 1) - __shfl(off_l, r);
        float nv = (dg > 0) ? rsqrtf((float)dg) : 0.0f;
        int gd = base + r;
        if (gd < n_dst) {
#pragma unroll
            for (int n = 0; n < 4; ++n)
                out[(size_t)gd * D_OUT + wv * 64 + n * 16 + lrow] = acc[n][j] * nv + bias_r[n];
        }
    }
}

extern "C" void kernel_launch(void* const* d_in, const int* in_sizes, int n_in,
                              void* d_out, int out_size, void* d_ws, size_t ws_size,
                              hipStream_t stream) {
    const float* src_feats  = (const float*)d_in[0];
    const float* edge_feats = (const float*)d_in[1];
    const int*   src_idx    = (const int*)d_in[2];
    const int*   dst_idx    = (const int*)d_in[3];
    const float* weights    = (const float*)d_in[4];
    const float* h_bias     = (const float*)d_in[5];

    const int E     = in_sizes[2];
    const int n_dst = out_size / D_OUT;
    float* out = (float*)d_out;

    char* ws = (char*)d_ws;
    unsigned short* wfrag = (unsigned short*)ws;            // 262144 B
    int2* rec       = (int2*)(ws + 262144);                 // E * 8 B
    int*  deg       = (int*)(ws + 262144 + (size_t)E * 8);
    int*  offsets   = deg + n_dst;                          // n_dst + 1
    int*  cursor    = offsets + n_dst + 1;                  // n_dst

    const int CB = (E + 255) / 256;
    const int ZB = (n_dst + 255) / 256;

    zero_wfrag_kernel<<<ZB + 64, 256, 0, stream>>>(deg, n_dst, ZB, weights, wfrag);
    count_kernel<<<CB, 256, 0, stream>>>(dst_idx, deg, E);
    scan_kernel<<<1, 1024, 0, stream>>>(deg, offsets, cursor, n_dst);
    scatter_kernel<<<CB, 256, 0, stream>>>(dst_idx, src_idx, cursor, rec, E);

    fused_kernel<<<(n_dst + TM - 1) / TM, 256, 0, stream>>>(
        src_feats, edge_feats, rec, offsets, wfrag, h_bias, out, n_dst);
}